// Round 5
// baseline (377.651 us; speedup 1.0000x reference)
//
#include <hip/hip_runtime.h>

#define HW 4096
#define EPS 1e-6f

// Barrier-free streaming formulation. The 3x3 wrapped stencil is over the
// CHANNEL dims (t in 0..7, d in 0..15) at fixed spatial position, so a thread
// that owns one spatial float4 across all 128 channels of a capsule computes
// the whole convolution thread-locally: rolling 3-row u^2 window (3 x 16
// float4) + pinned row 0 (t-wrap) in registers. No LDS, no __syncthreads,
// no vmcnt(0)-drain phases -- loads stream continuously (the structure of the
// 4.9-5.2 TB/s norm kernels), which R0-R4's bulk-synchronous versions never had.
__device__ __forceinline__ void fma4(float4& a, float s, const float4& v) {
    a.x = fmaf(s, v.x, a.x);
    a.y = fmaf(s, v.y, a.y);
    a.z = fmaf(s, v.z, a.z);
    a.w = fmaf(s, v.w, a.w);
}

__global__ __launch_bounds__(256, 1) void caps_norm_kernel(
    const float* __restrict__ z, const float* __restrict__ u,
    const float* __restrict__ w, const float* __restrict__ beta,
    float* __restrict__ out)
{
    const int tid = threadIdx.x;
    const int bid = blockIdx.x;            // ((b*16 + c)*4 + pg)
    const int pg  = bid & 3;
    const int c   = (bid >> 2) & 15;
    const int b   = bid >> 6;
    const int p   = (pg << 10) + (tid << 2);   // spatial float4 start, 0..4092

    float W9[9];
#pragma unroll
    for (int i = 0; i < 9; ++i) W9[i] = w[i];
    const float bet = beta[0];

    // channel (t,d) of capsule c lives at ch = t*256 + c*16 + d
    const size_t base = ((size_t)b * 2048 + (size_t)c * 16) * HW + p;
    const float* up = u + base;
    const float* zp = z + base;
    float*       op = out + base;

    // rolling window slots (u^2) + pinned row 0 for the t-wrap
    float4 A[16], B[16], C[16], PIN[16];

#define LOADROW(DST, T)                                                      \
    _Pragma("unroll")                                                        \
    for (int d = 0; d < 16; ++d)                                             \
        DST[d] = *(const float4*)(up + ((T) * 256 + d) * HW);

#define SQR(DST)                                                             \
    _Pragma("unroll")                                                        \
    for (int d = 0; d < 16; ++d) {                                           \
        DST[d].x *= DST[d].x; DST[d].y *= DST[d].y;                          \
        DST[d].z *= DST[d].z; DST[d].w *= DST[d].w;                          \
    }

    // COMP(T, rows t-1, t, t+1): v = sum_{i,j} W[i][j]*usq[t+i-1][(d+j-1)%16]
#define COMP(T, W0, W1, W2)                                                  \
    _Pragma("unroll")                                                        \
    for (int d = 0; d < 16; ++d) {                                           \
        const int dm = (d + 15) & 15, dp = (d + 1) & 15;                     \
        const float4 z4 = *(const float4*)(zp + ((T) * 256 + d) * HW);       \
        float4 acc = make_float4(0.f, 0.f, 0.f, 0.f);                        \
        fma4(acc, W9[0], W0[dm]); fma4(acc, W9[1], W0[d]); fma4(acc, W9[2], W0[dp]); \
        fma4(acc, W9[3], W1[dm]); fma4(acc, W9[4], W1[d]); fma4(acc, W9[5], W1[dp]); \
        fma4(acc, W9[6], W2[dm]); fma4(acc, W9[7], W2[d]); fma4(acc, W9[8], W2[dp]); \
        float4 o;                                                            \
        o.x = (z4.x + bet) * rsqrtf(acc.x + EPS);                            \
        o.y = (z4.y + bet) * rsqrtf(acc.y + EPS);                            \
        o.z = (z4.z + bet) * rsqrtf(acc.z + EPS);                            \
        o.w = (z4.w + bet) * rsqrtf(acc.w + EPS);                            \
        *(float4*)(op + ((T) * 256 + d) * HW) = o;                           \
    }

    // prologue: rows 7, 0, 1, 2 in flight together (64 independent loads)
    LOADROW(A, 7)
    LOADROW(PIN, 0)
    LOADROW(B, 1)
    LOADROW(C, 2)
    SQR(A) SQR(PIN)

    // steady state: square row t+1, compute row t, then issue the next load
    // into the slot whose row just died (WAR-safe; covered by next step's FMAs)
    SQR(B)  COMP(0, A, PIN, B)  LOADROW(A, 3)
    SQR(C)  COMP(1, PIN, B, C)
    SQR(A)  COMP(2, B, C, A)    LOADROW(B, 4)
    SQR(B)  COMP(3, C, A, B)    LOADROW(C, 5)
    SQR(C)  COMP(4, A, B, C)    LOADROW(A, 6)
    SQR(A)  COMP(5, B, C, A)    LOADROW(B, 7)   // row 7 reloaded (t-wrap)
    SQR(B)  COMP(6, C, A, B)
            COMP(7, A, B, PIN)                   // t-wrap: row 8 == row 0

#undef LOADROW
#undef SQR
#undef COMP
}

extern "C" void kernel_launch(void* const* d_in, const int* in_sizes, int n_in,
                              void* d_out, int out_size, void* d_ws, size_t ws_size,
                              hipStream_t stream) {
    const float* z    = (const float*)d_in[0];
    const float* u    = (const float*)d_in[1];
    const float* w    = (const float*)d_in[2];
    const float* beta = (const float*)d_in[3];
    float* out = (float*)d_out;

    // 65536 threads: one float4 x 128 channels each.
    // grid = B(4) * N_CAPS(16) * (HW/1024 = 4) = 256 blocks x 256 threads
    caps_norm_kernel<<<dim3(256), dim3(256), 0, stream>>>(z, u, w, beta, out);
}